// Round 10
// baseline (753.426 us; speedup 1.0000x reference)
//
#include <hip/hip_runtime.h>
#include <stdint.h>

typedef unsigned short ushort_t;

#define M_DIM 8192
#define N_DIM 4096
#define K_DIM 4096
#define N_W   (N_DIM * K_DIM)      // 16777216 weights
#define RANK_LO 15938354           // floor(0.95 * (N_W - 1))
#define RANK_HI 15938355

// ---- workspace layout (bytes) ----
#define WS_CTRL   0u
#define WS_H1     1024u                      // 2048 x u32
#define WS_H2A    16384u                     // 65536 x u32
#define WS_H2B    (16384u + 262144u)
#define WS_LISTA  540672u                    // 1024 x u32
#define WS_LISTB  544768u
#define WS_ZERO_BYTES 540672u                // ctrl + H1 + H2A + H2B
#define WS_ABF    (1u << 20)                 // 64 MiB bf16 A
#define WS_WBF    ((1u << 20) + 67108864u)   // 32 MiB bf16 masked W
#define WS_NEED   ((size_t)(1u << 20) + 67108864u + 33554432u)

// ctrl word indices
#define C_C0 0
#define C_R0 1
#define C_C1 2
#define C_R1 3
#define C_M0 4
#define C_R0B 5
#define C_M1 6
#define C_R1B 7
#define C_CNTA 8
#define C_CNTB 9
#define C_TBITS 10

__device__ __forceinline__ ushort_t f2bf(float f) {   // round-to-nearest-even
    uint32_t x = __float_as_uint(f);
    uint32_t r = (x + 0x7FFFu + ((x >> 16) & 1u)) >> 16;
    return (ushort_t)r;
}

// ---------------- Phase A: exact order statistic of |w| ----------------

__global__ void k_hist1(const uint32_t* __restrict__ w, uint32_t* __restrict__ h1) {
    __shared__ uint32_t lh[2048];
    for (int i = threadIdx.x; i < 2048; i += 256) lh[i] = 0;
    __syncthreads();
    const uint4* w4 = (const uint4*)w;
    const int n4 = N_W / 4;
    for (int i = blockIdx.x * 256 + threadIdx.x; i < n4; i += gridDim.x * 256) {
        uint4 v = w4[i];
        atomicAdd(&lh[(v.x & 0x7FFFFFFFu) >> 20], 1u);
        atomicAdd(&lh[(v.y & 0x7FFFFFFFu) >> 20], 1u);
        atomicAdd(&lh[(v.z & 0x7FFFFFFFu) >> 20], 1u);
        atomicAdd(&lh[(v.w & 0x7FFFFFFFu) >> 20], 1u);
    }
    __syncthreads();
    for (int i = threadIdx.x; i < 2048; i += 256)
        if (lh[i]) atomicAdd(&h1[i], lh[i]);
}

__global__ void k_sel1(const uint32_t* __restrict__ h1, uint32_t* __restrict__ ctrl) {
    __shared__ uint32_t part[256];
    __shared__ uint32_t ex[256];
    int t = threadIdx.x;
    uint32_t loc[8];
    uint32_t s = 0;
    for (int j = 0; j < 8; j++) { loc[j] = h1[t * 8 + j]; s += loc[j]; }
    part[t] = s;
    __syncthreads();
    if (t == 0) { uint32_t c = 0; for (int i = 0; i < 256; i++) { ex[i] = c; c += part[i]; } }
    __syncthreads();
    uint32_t cum = ex[t];
    for (int j = 0; j < 8; j++) {
        uint32_t c = loc[j];
        if (RANK_LO >= cum && RANK_LO < cum + c) { ctrl[C_C0] = t * 8 + j; ctrl[C_R0] = RANK_LO - cum; }
        if (RANK_HI >= cum && RANK_HI < cum + c) { ctrl[C_C1] = t * 8 + j; ctrl[C_R1] = RANK_HI - cum; }
        cum += c;
    }
}

__global__ void k_hist2(const uint32_t* __restrict__ w, const uint32_t* __restrict__ ctrl,
                        uint32_t* __restrict__ h2a, uint32_t* __restrict__ h2b) {
    uint32_t c0 = ctrl[C_C0], c1 = ctrl[C_C1];
    const uint4* w4 = (const uint4*)w;
    const int n4 = N_W / 4;
    for (int i = blockIdx.x * 256 + threadIdx.x; i < n4; i += gridDim.x * 256) {
        uint4 v = w4[i];
        uint32_t u;
        u = v.x & 0x7FFFFFFFu; if ((u >> 20) == c0) atomicAdd(&h2a[(u >> 4) & 0xFFFFu], 1u); if ((u >> 20) == c1) atomicAdd(&h2b[(u >> 4) & 0xFFFFu], 1u);
        u = v.y & 0x7FFFFFFFu; if ((u >> 20) == c0) atomicAdd(&h2a[(u >> 4) & 0xFFFFu], 1u); if ((u >> 20) == c1) atomicAdd(&h2b[(u >> 4) & 0xFFFFu], 1u);
        u = v.z & 0x7FFFFFFFu; if ((u >> 20) == c0) atomicAdd(&h2a[(u >> 4) & 0xFFFFu], 1u); if ((u >> 20) == c1) atomicAdd(&h2b[(u >> 4) & 0xFFFFu], 1u);
        u = v.w & 0x7FFFFFFFu; if ((u >> 20) == c0) atomicAdd(&h2a[(u >> 4) & 0xFFFFu], 1u); if ((u >> 20) == c1) atomicAdd(&h2b[(u >> 4) & 0xFFFFu], 1u);
    }
}

__global__ void k_sel2(const uint32_t* __restrict__ h2a, const uint32_t* __restrict__ h2b,
                       uint32_t* __restrict__ ctrl) {
    __shared__ uint32_t part[256];
    __shared__ uint32_t ex[256];
    int t = threadIdx.x;
    for (int which = 0; which < 2; which++) {
        const uint32_t* h = which ? h2b : h2a;
        uint32_t target = ctrl[which ? C_R1 : C_R0];
        uint32_t s = 0;
        for (int j = 0; j < 256; j++) s += h[t * 256 + j];
        part[t] = s;
        __syncthreads();
        if (t == 0) { uint32_t c = 0; for (int i = 0; i < 256; i++) { ex[i] = c; c += part[i]; } }
        __syncthreads();
        uint32_t cum = ex[t];
        for (int j = 0; j < 256; j++) {
            uint32_t c = h[t * 256 + j];
            if (target >= cum && target < cum + c) {
                ctrl[which ? C_M1 : C_M0]  = t * 256 + j;
                ctrl[which ? C_R1B : C_R0B] = target - cum;
            }
            cum += c;
        }
        __syncthreads();
    }
}

__global__ void k_gather(const uint32_t* __restrict__ w, uint32_t* __restrict__ ctrl,
                         uint32_t* __restrict__ listA, uint32_t* __restrict__ listB) {
    uint32_t keyA = (ctrl[C_C0] << 16) | ctrl[C_M0];
    uint32_t keyB = (ctrl[C_C1] << 16) | ctrl[C_M1];
    const uint4* w4 = (const uint4*)w;
    const int n4 = N_W / 4;
    for (int i = blockIdx.x * 256 + threadIdx.x; i < n4; i += gridDim.x * 256) {
        uint4 v = w4[i];
        uint32_t u;
        u = v.x & 0x7FFFFFFFu;
        if ((u >> 4) == keyA) { uint32_t p = atomicAdd(&ctrl[C_CNTA], 1u); if (p < 1024) listA[p] = u; }
        if ((u >> 4) == keyB) { uint32_t p = atomicAdd(&ctrl[C_CNTB], 1u); if (p < 1024) listB[p] = u; }
        u = v.y & 0x7FFFFFFFu;
        if ((u >> 4) == keyA) { uint32_t p = atomicAdd(&ctrl[C_CNTA], 1u); if (p < 1024) listA[p] = u; }
        if ((u >> 4) == keyB) { uint32_t p = atomicAdd(&ctrl[C_CNTB], 1u); if (p < 1024) listB[p] = u; }
        u = v.z & 0x7FFFFFFFu;
        if ((u >> 4) == keyA) { uint32_t p = atomicAdd(&ctrl[C_CNTA], 1u); if (p < 1024) listA[p] = u; }
        if ((u >> 4) == keyB) { uint32_t p = atomicAdd(&ctrl[C_CNTB], 1u); if (p < 1024) listB[p] = u; }
        u = v.w & 0x7FFFFFFFu;
        if ((u >> 4) == keyA) { uint32_t p = atomicAdd(&ctrl[C_CNTA], 1u); if (p < 1024) listA[p] = u; }
        if ((u >> 4) == keyB) { uint32_t p = atomicAdd(&ctrl[C_CNTB], 1u); if (p < 1024) listB[p] = u; }
    }
}

__global__ void k_final(const uint32_t* __restrict__ listA, const uint32_t* __restrict__ listB,
                        uint32_t* __restrict__ ctrl) {
    __shared__ uint32_t res[2];
    int lane = threadIdx.x;   // 64 threads
    for (int which = 0; which < 2; which++) {
        const uint32_t* lst = which ? listB : listA;
        uint32_t n = ctrl[which ? C_CNTB : C_CNTA];
        if (n > 1024u) n = 1024u;
        uint32_t k = ctrl[which ? C_R1B : C_R0B];
        for (uint32_t i = lane; i < n; i += 64) {
            uint32_t x = lst[i];
            uint32_t lo = 0, eq = 0;
            for (uint32_t j = 0; j < n; j++) { uint32_t y = lst[j]; lo += (y < x); eq += (y == x); }
            if (lo <= k && k < lo + eq) res[which] = x;
        }
        __syncthreads();
    }
    if (lane == 0) {
        // R9 post-mortem: absmax 9.25 == one-boundary-weight signature.
        // np reference's effective mask INCLUDES the lower order statistic a
        // (rank RANK_LO) => threshold = a (res[0]), mask |w| >= a.
        ctrl[C_TBITS] = res[0];
    }
}

// ---------------- Phase B: conversions ----------------

__global__ void k_convA(const float4* __restrict__ x, ushort4* __restrict__ y, int n4) {
    for (int i = blockIdx.x * 256 + threadIdx.x; i < n4; i += gridDim.x * 256) {
        float4 v = x[i];
        ushort4 o;
        o.x = f2bf(v.x); o.y = f2bf(v.y); o.z = f2bf(v.z); o.w = f2bf(v.w);
        y[i] = o;
    }
}

__global__ void k_maskW(const float4* __restrict__ w, const uint32_t* __restrict__ ctrl,
                        ushort4* __restrict__ y, int n4) {
    float T = __uint_as_float(ctrl[C_TBITS]);
    for (int i = blockIdx.x * 256 + threadIdx.x; i < n4; i += gridDim.x * 256) {
        float4 v = w[i];
        ushort4 o;
        o.x = (fabsf(v.x) >= T) ? f2bf(v.x) : (ushort_t)0;
        o.y = (fabsf(v.y) >= T) ? f2bf(v.y) : (ushort_t)0;
        o.z = (fabsf(v.z) >= T) ? f2bf(v.z) : (ushort_t)0;
        o.w = (fabsf(v.w) >= T) ? f2bf(v.w) : (ushort_t)0;
        y[i] = o;
    }
}

// ---------------- Phase C: bf16 MFMA GEMM  (C = A * B^T + bias) ----------------
// A: [M][K] bf16, B: [N][K] bf16 (weight layout), C: [M][N] f32

typedef __bf16 bf16x8 __attribute__((ext_vector_type(8)));
typedef float  f32x4  __attribute__((ext_vector_type(4)));
typedef short  s16x8  __attribute__((ext_vector_type(8)));

union FragCvt { s16x8 s; bf16x8 b; };

__device__ __forceinline__ void gload_lds16(const void* g, void* lds) {
    __builtin_amdgcn_global_load_lds(
        (const __attribute__((address_space(1))) void*)(uintptr_t)g,
        (__attribute__((address_space(3))) void*)(uintptr_t)lds,
        16, 0, 0);
}

__global__ __launch_bounds__(256) void k_gemm(
    const ushort_t* __restrict__ A, const ushort_t* __restrict__ B,
    const float* __restrict__ bias, float* __restrict__ C) {
    __shared__ __align__(16) short lsA[128 * 32];
    __shared__ __align__(16) short lsB[128 * 32];

    const int tid  = threadIdx.x;
    const int lane = tid & 63;
    const int wid  = tid >> 6;            // 0..3
    const int wm   = wid >> 1, wn = wid & 1;

    // XCD-aware bijective swizzle (2048 blocks % 8 == 0)
    int bid = blockIdx.x;
    bid = (bid & 7) * 256 + (bid >> 3);
    const int bm = bid / (N_DIM / 128);
    const int bn = bid % (N_DIM / 128);

    f32x4 acc[4][4] = {};

    const char* gA = (const char*)A + (size_t)bm * 128 * (K_DIM * 2);
    const char* gB = (const char*)B + (size_t)bn * 128 * (K_DIM * 2);
    const int r0 = lane >> 2;             // staging row-within-16
    const int cb = (lane & 3) * 16;       // staging byte-col
    const int lr = lane & 15;
    const int lk = lane >> 4;             // 0..3

    for (int k0 = 0; k0 < K_DIM; k0 += 32) {
        __syncthreads();                  // previous tile's reads done
#pragma unroll
        for (int j = 0; j < 2; j++) {
            const int idx = wid * 2 + j;  // 0..7 covers 128 rows
            const int row = idx * 16 + r0;
            gload_lds16(gA + (size_t)row * (K_DIM * 2) + k0 * 2 + cb, &lsA[idx * 512]);
            gload_lds16(gB + (size_t)row * (K_DIM * 2) + k0 * 2 + cb, &lsB[idx * 512]);
        }
        __syncthreads();                  // compiler drains vmcnt before barrier

        FragCvt a[4], b[4];
#pragma unroll
        for (int m = 0; m < 4; m++) {
            a[m].s = *(const s16x8*)&lsA[(wm * 64 + m * 16 + lr) * 32 + lk * 8];
            b[m].s = *(const s16x8*)&lsB[(wn * 64 + m * 16 + lr) * 32 + lk * 8];
        }
#pragma unroll
        for (int m = 0; m < 4; m++)
#pragma unroll
            for (int n = 0; n < 4; n++)
                acc[m][n] = __builtin_amdgcn_mfma_f32_16x16x32_bf16(a[m].b, b[n].b, acc[m][n], 0, 0, 0);
    }

    const int colbase = bn * 128 + wn * 64 + lr;
    const int rowbase = bm * 128 + wm * 64 + lk * 4;
#pragma unroll
    for (int n = 0; n < 4; n++) {
        float bv = bias[colbase + n * 16];
#pragma unroll
        for (int m = 0; m < 4; m++) {
#pragma unroll
            for (int r = 0; r < 4; r++)
                C[(size_t)(rowbase + m * 16 + r) * N_DIM + colbase + n * 16] = acc[m][n][r] + bv;
        }
    }
}

// ---------------- fallback (tiny ws): masked f32 GEMM ----------------
__global__ void k_gemm_f32(const float* __restrict__ A, const float* __restrict__ W,
                           const uint32_t* __restrict__ ctrl, const float* __restrict__ bias,
                           float* __restrict__ C) {
    __shared__ float sA[16][64];
    __shared__ float sW[16][65];
    float T = __uint_as_float(ctrl[C_TBITS]);
    int bx = blockIdx.x % (N_DIM / 16), by = blockIdx.x / (N_DIM / 16);
    int tx = threadIdx.x & 15, ty = threadIdx.x >> 4;
    float acc = 0.f;
    for (int k0 = 0; k0 < K_DIM; k0 += 64) {
        for (int j = threadIdx.x; j < 16 * 64; j += 256) {
            int r = j >> 6, c = j & 63;
            sA[r][c] = A[(size_t)(by * 16 + r) * K_DIM + k0 + c];
            float w = W[(size_t)(bx * 16 + r) * K_DIM + k0 + c];
            sW[r][c] = (fabsf(w) >= T) ? w : 0.f;
        }
        __syncthreads();
#pragma unroll 16
        for (int kk = 0; kk < 64; kk++) acc += sA[ty][kk] * sW[tx][kk];
        __syncthreads();
    }
    C[(size_t)(by * 16 + ty) * N_DIM + bx * 16 + tx] = acc + bias[bx * 16 + tx];
}

extern "C" void kernel_launch(void* const* d_in, const int* in_sizes, int n_in,
                              void* d_out, int out_size, void* d_ws, size_t ws_size,
                              hipStream_t stream) {
    const float* x    = (const float*)d_in[0];
    const float* w    = (const float*)d_in[1];
    const float* bias = (const float*)d_in[2];
    float* out = (float*)d_out;
    char* ws = (char*)d_ws;

    uint32_t* ctrl  = (uint32_t*)(ws + WS_CTRL);
    uint32_t* h1    = (uint32_t*)(ws + WS_H1);
    uint32_t* h2a   = (uint32_t*)(ws + WS_H2A);
    uint32_t* h2b   = (uint32_t*)(ws + WS_H2B);
    uint32_t* listA = (uint32_t*)(ws + WS_LISTA);
    uint32_t* listB = (uint32_t*)(ws + WS_LISTB);

    hipMemsetAsync(d_ws, 0, WS_ZERO_BYTES, stream);
    k_hist1 <<<1024, 256, 0, stream>>>((const uint32_t*)w, h1);
    k_sel1  <<<1,    256, 0, stream>>>(h1, ctrl);
    k_hist2 <<<1024, 256, 0, stream>>>((const uint32_t*)w, ctrl, h2a, h2b);
    k_sel2  <<<1,    256, 0, stream>>>(h2a, h2b, ctrl);
    k_gather<<<1024, 256, 0, stream>>>((const uint32_t*)w, ctrl, listA, listB);
    k_final <<<1,     64, 0, stream>>>(listA, listB, ctrl);

    if (ws_size >= WS_NEED) {
        ushort_t* Abf = (ushort_t*)(ws + WS_ABF);
        ushort_t* Wbf = (ushort_t*)(ws + WS_WBF);
        k_convA<<<2048, 256, 0, stream>>>((const float4*)x, (ushort4*)Abf, (M_DIM * K_DIM) / 4);
        k_maskW<<<1024, 256, 0, stream>>>((const float4*)w, ctrl, (ushort4*)Wbf, N_W / 4);
        k_gemm <<<(M_DIM / 128) * (N_DIM / 128), 256, 0, stream>>>(Abf, Wbf, bias, out);
    } else {
        k_gemm_f32<<<(M_DIM / 16) * (N_DIM / 16), 256, 0, stream>>>(x, w, ctrl, bias, out);
    }
}

// Round 13
// 656.502 us; speedup vs baseline: 1.1476x; 1.1476x over previous
//
#include <hip/hip_runtime.h>
#include <stdint.h>

typedef unsigned short ushort_t;

#define M_DIM 8192
#define N_DIM 4096
#define K_DIM 4096
#define N_W   (N_DIM * K_DIM)      // 16777216 weights
#define RANK_LO 15938354           // floor(0.95 * (N_W - 1))
#define RANK_HI 15938355

// ---- workspace layout (bytes) ----
#define WS_CTRL   0u
#define WS_H1     1024u                      // 2048 x u32
#define WS_H2A    16384u                     // 65536 x u32
#define WS_H2B    (16384u + 262144u)
#define WS_LISTA  540672u                    // 1024 x u32
#define WS_LISTB  544768u
#define WS_ZERO_BYTES 540672u                // ctrl + H1 + H2A + H2B
#define WS_ABF    (1u << 20)                 // 64 MiB bf16 A
#define WS_WBF    ((1u << 20) + 67108864u)   // 32 MiB bf16 masked W
#define WS_NEED   ((size_t)(1u << 20) + 67108864u + 33554432u)

// ctrl word indices
#define C_C0 0
#define C_R0 1
#define C_C1 2
#define C_R1 3
#define C_M0 4
#define C_R0B 5
#define C_M1 6
#define C_R1B 7
#define C_CNTA 8
#define C_CNTB 9
#define C_TBITS 10

__device__ __forceinline__ ushort_t f2bf(float f) {   // round-to-nearest-even
    uint32_t x = __float_as_uint(f);
    uint32_t r = (x + 0x7FFFu + ((x >> 16) & 1u)) >> 16;
    return (ushort_t)r;
}

// ---------------- Phase A: exact order statistic of |w| ----------------

__global__ void k_hist1(const uint32_t* __restrict__ w, uint32_t* __restrict__ h1) {
    __shared__ uint32_t lh[2048];
    for (int i = threadIdx.x; i < 2048; i += 256) lh[i] = 0;
    __syncthreads();
    const uint4* w4 = (const uint4*)w;
    const int n4 = N_W / 4;
    for (int i = blockIdx.x * 256 + threadIdx.x; i < n4; i += gridDim.x * 256) {
        uint4 v = w4[i];
        atomicAdd(&lh[(v.x & 0x7FFFFFFFu) >> 20], 1u);
        atomicAdd(&lh[(v.y & 0x7FFFFFFFu) >> 20], 1u);
        atomicAdd(&lh[(v.z & 0x7FFFFFFFu) >> 20], 1u);
        atomicAdd(&lh[(v.w & 0x7FFFFFFFu) >> 20], 1u);
    }
    __syncthreads();
    for (int i = threadIdx.x; i < 2048; i += 256)
        if (lh[i]) atomicAdd(&h1[i], lh[i]);
}

__global__ void k_sel1(const uint32_t* __restrict__ h1, uint32_t* __restrict__ ctrl) {
    __shared__ uint32_t part[256];
    __shared__ uint32_t ex[256];
    int t = threadIdx.x;
    uint32_t loc[8];
    uint32_t s = 0;
    for (int j = 0; j < 8; j++) { loc[j] = h1[t * 8 + j]; s += loc[j]; }
    part[t] = s;
    __syncthreads();
    if (t == 0) { uint32_t c = 0; for (int i = 0; i < 256; i++) { ex[i] = c; c += part[i]; } }
    __syncthreads();
    uint32_t cum = ex[t];
    for (int j = 0; j < 8; j++) {
        uint32_t c = loc[j];
        if (RANK_LO >= cum && RANK_LO < cum + c) { ctrl[C_C0] = t * 8 + j; ctrl[C_R0] = RANK_LO - cum; }
        if (RANK_HI >= cum && RANK_HI < cum + c) { ctrl[C_C1] = t * 8 + j; ctrl[C_R1] = RANK_HI - cum; }
        cum += c;
    }
}

__global__ void k_hist2(const uint32_t* __restrict__ w, const uint32_t* __restrict__ ctrl,
                        uint32_t* __restrict__ h2a, uint32_t* __restrict__ h2b) {
    uint32_t c0 = ctrl[C_C0], c1 = ctrl[C_C1];
    const uint4* w4 = (const uint4*)w;
    const int n4 = N_W / 4;
    for (int i = blockIdx.x * 256 + threadIdx.x; i < n4; i += gridDim.x * 256) {
        uint4 v = w4[i];
        uint32_t u;
        u = v.x & 0x7FFFFFFFu; if ((u >> 20) == c0) atomicAdd(&h2a[(u >> 4) & 0xFFFFu], 1u); if ((u >> 20) == c1) atomicAdd(&h2b[(u >> 4) & 0xFFFFu], 1u);
        u = v.y & 0x7FFFFFFFu; if ((u >> 20) == c0) atomicAdd(&h2a[(u >> 4) & 0xFFFFu], 1u); if ((u >> 20) == c1) atomicAdd(&h2b[(u >> 4) & 0xFFFFu], 1u);
        u = v.z & 0x7FFFFFFFu; if ((u >> 20) == c0) atomicAdd(&h2a[(u >> 4) & 0xFFFFu], 1u); if ((u >> 20) == c1) atomicAdd(&h2b[(u >> 4) & 0xFFFFu], 1u);
        u = v.w & 0x7FFFFFFFu; if ((u >> 20) == c0) atomicAdd(&h2a[(u >> 4) & 0xFFFFu], 1u); if ((u >> 20) == c1) atomicAdd(&h2b[(u >> 4) & 0xFFFFu], 1u);
    }
}

__global__ void k_sel2(const uint32_t* __restrict__ h2a, const uint32_t* __restrict__ h2b,
                       uint32_t* __restrict__ ctrl) {
    __shared__ uint32_t part[256];
    __shared__ uint32_t ex[256];
    int t = threadIdx.x;
    for (int which = 0; which < 2; which++) {
        const uint32_t* h = which ? h2b : h2a;
        uint32_t target = ctrl[which ? C_R1 : C_R0];
        uint32_t s = 0;
        for (int j = 0; j < 256; j++) s += h[t * 256 + j];
        part[t] = s;
        __syncthreads();
        if (t == 0) { uint32_t c = 0; for (int i = 0; i < 256; i++) { ex[i] = c; c += part[i]; } }
        __syncthreads();
        uint32_t cum = ex[t];
        for (int j = 0; j < 256; j++) {
            uint32_t c = h[t * 256 + j];
            if (target >= cum && target < cum + c) {
                ctrl[which ? C_M1 : C_M0]  = t * 256 + j;
                ctrl[which ? C_R1B : C_R0B] = target - cum;
            }
            cum += c;
        }
        __syncthreads();
    }
}

__global__ void k_gather(const uint32_t* __restrict__ w, uint32_t* __restrict__ ctrl,
                         uint32_t* __restrict__ listA, uint32_t* __restrict__ listB) {
    uint32_t keyA = (ctrl[C_C0] << 16) | ctrl[C_M0];
    uint32_t keyB = (ctrl[C_C1] << 16) | ctrl[C_M1];
    const uint4* w4 = (const uint4*)w;
    const int n4 = N_W / 4;
    for (int i = blockIdx.x * 256 + threadIdx.x; i < n4; i += gridDim.x * 256) {
        uint4 v = w4[i];
        uint32_t u;
        u = v.x & 0x7FFFFFFFu;
        if ((u >> 4) == keyA) { uint32_t p = atomicAdd(&ctrl[C_CNTA], 1u); if (p < 1024) listA[p] = u; }
        if ((u >> 4) == keyB) { uint32_t p = atomicAdd(&ctrl[C_CNTB], 1u); if (p < 1024) listB[p] = u; }
        u = v.y & 0x7FFFFFFFu;
        if ((u >> 4) == keyA) { uint32_t p = atomicAdd(&ctrl[C_CNTA], 1u); if (p < 1024) listA[p] = u; }
        if ((u >> 4) == keyB) { uint32_t p = atomicAdd(&ctrl[C_CNTB], 1u); if (p < 1024) listB[p] = u; }
        u = v.z & 0x7FFFFFFFu;
        if ((u >> 4) == keyA) { uint32_t p = atomicAdd(&ctrl[C_CNTA], 1u); if (p < 1024) listA[p] = u; }
        if ((u >> 4) == keyB) { uint32_t p = atomicAdd(&ctrl[C_CNTB], 1u); if (p < 1024) listB[p] = u; }
        u = v.w & 0x7FFFFFFFu;
        if ((u >> 4) == keyA) { uint32_t p = atomicAdd(&ctrl[C_CNTA], 1u); if (p < 1024) listA[p] = u; }
        if ((u >> 4) == keyB) { uint32_t p = atomicAdd(&ctrl[C_CNTB], 1u); if (p < 1024) listB[p] = u; }
    }
}

__global__ void k_final(const uint32_t* __restrict__ listA, const uint32_t* __restrict__ listB,
                        uint32_t* __restrict__ ctrl) {
    __shared__ uint32_t res[2];
    int lane = threadIdx.x;   // 64 threads
    for (int which = 0; which < 2; which++) {
        const uint32_t* lst = which ? listB : listA;
        uint32_t n = ctrl[which ? C_CNTB : C_CNTA];
        if (n > 1024u) n = 1024u;
        uint32_t k = ctrl[which ? C_R1B : C_R0B];
        for (uint32_t i = lane; i < n; i += 64) {
            uint32_t x = lst[i];
            uint32_t lo = 0, eq = 0;
            for (uint32_t j = 0; j < n; j++) { uint32_t y = lst[j]; lo += (y < x); eq += (y == x); }
            if (lo <= k && k < lo + eq) res[which] = x;
        }
        __syncthreads();
    }
    if (lane == 0) {
        // R9 post-mortem (confirmed R10 PASS): np reference's effective mask
        // includes the lower order statistic a (rank RANK_LO) => T = a.
        ctrl[C_TBITS] = res[0];
    }
}

// ---------------- Phase B: conversions ----------------

__global__ void k_convA(const float4* __restrict__ x, ushort4* __restrict__ y, int n4) {
    for (int i = blockIdx.x * 256 + threadIdx.x; i < n4; i += gridDim.x * 256) {
        float4 v = x[i];
        ushort4 o;
        o.x = f2bf(v.x); o.y = f2bf(v.y); o.z = f2bf(v.z); o.w = f2bf(v.w);
        y[i] = o;
    }
}

__global__ void k_maskW(const float4* __restrict__ w, const uint32_t* __restrict__ ctrl,
                        ushort4* __restrict__ y, int n4) {
    float T = __uint_as_float(ctrl[C_TBITS]);
    for (int i = blockIdx.x * 256 + threadIdx.x; i < n4; i += gridDim.x * 256) {
        float4 v = w[i];
        ushort4 o;
        o.x = (fabsf(v.x) >= T) ? f2bf(v.x) : (ushort_t)0;
        o.y = (fabsf(v.y) >= T) ? f2bf(v.y) : (ushort_t)0;
        o.z = (fabsf(v.z) >= T) ? f2bf(v.z) : (ushort_t)0;
        o.w = (fabsf(v.w) >= T) ? f2bf(v.w) : (ushort_t)0;
        y[i] = o;
    }
}

// ---------------- Phase C: 256^2 8-phase bf16 MFMA GEMM (C = A*B^T + bias) ----
// A: [M][K] bf16, B: [N][K] bf16 (weight layout), C: [M][N] f32
// Structure: BM=BN=256, BK=64, 512 thr (8 waves = 2Mx4N), LDS 128 KiB
// [dbuf][A/B][khalf][256][32] bf16, T2 swizzle col ^= ((row>>1)&3)<<3,
// counted vmcnt(4) (never 0 in loop), raw s_barrier, setprio around MFMA.

typedef __bf16 bf16x8 __attribute__((ext_vector_type(8)));
typedef float  f32x4  __attribute__((ext_vector_type(4)));
typedef short  s16x8  __attribute__((ext_vector_type(8)));

union FragCvt { s16x8 s; bf16x8 b; };

__device__ __forceinline__ void gload_lds16(const void* g, void* lds) {
    __builtin_amdgcn_global_load_lds(
        (const __attribute__((address_space(1))) void*)(uintptr_t)g,
        (__attribute__((address_space(3))) void*)(uintptr_t)lds,
        16, 0, 0);
}

#define SBAR  __builtin_amdgcn_s_barrier()
#define WVM4  asm volatile("s_waitcnt vmcnt(4)" ::: "memory")

__global__ __launch_bounds__(512, 1) void k_gemm256(
    const ushort_t* __restrict__ A, const ushort_t* __restrict__ B,
    const float* __restrict__ bias, float* __restrict__ C) {
    __shared__ __align__(16) short lsg[65536];   // 128 KiB

    const int tid  = threadIdx.x;
    const int wid  = tid >> 6;            // 0..7
    const int lane = tid & 63;
    const int wm   = wid >> 2;            // 0..1  (128 rows of C each)
    const int wn   = wid & 3;             // 0..3  (64 cols each)
    const int lr   = lane & 15;
    const int lk   = lane >> 4;           // 0..3
    const int srow = tid >> 2;            // 0..127 staging row within sweep
    const int scol = (tid & 3) * 8;       // staging col (shorts)

    // XCD-aware swizzle: 512 blocks, 512%8==0
    int bid = blockIdx.x;
    bid = (bid & 7) * 64 + (bid >> 3);
    const int bm = bid >> 4;              // 0..31  (M/256)
    const int bn = bid & 15;              // 0..15  (N/256)

    const ushort_t* gA = A + (size_t)bm * 256 * K_DIM;
    const ushort_t* gB = B + (size_t)bn * 256 * K_DIM;

    f32x4 acc[8][4] = {};

    // stage one half-tile (ab,kh) of K-tile kt into dbuf: 2 sweeps x gload16
    #define STAGE(dbuf, ab, kh, kt, G)                                          \
        _Pragma("unroll")                                                       \
        for (int s = 0; s < 2; s++) {                                           \
            int row = s * 128 + srow;                                           \
            int col = scol ^ (((row >> 1) & 3) << 3);                           \
            const ushort_t* src = (G) + (size_t)row * K_DIM + (kt) * 64 + (kh) * 32 + col; \
            gload_lds16(src, &lsg[(dbuf) * 32768 + (ab) * 16384 + (kh) * 8192 + s * 4096 + wid * 512]); \
        }

    #define LDA4(dst, dbuf, kh, mbase)                                          \
        _Pragma("unroll")                                                       \
        for (int m = 0; m < 4; m++) {                                           \
            int row = wm * 128 + ((mbase) + m) * 16 + lr;                       \
            int col = (lk * 8) ^ (((row >> 1) & 3) << 3);                       \
            dst[m].s = *(const s16x8*)&lsg[(dbuf) * 32768 + (kh) * 8192 + row * 32 + col]; \
        }

    #define LDB4(dst, dbuf, kh)                                                 \
        _Pragma("unroll")                                                       \
        for (int n = 0; n < 4; n++) {                                           \
            int row = wn * 64 + n * 16 + lr;                                    \
            int col = (lk * 8) ^ (((row >> 1) & 3) << 3);                       \
            dst[n].s = *(const s16x8*)&lsg[(dbuf) * 32768 + 16384 + (kh) * 8192 + row * 32 + col]; \
        }

    #define MM16(af, bf, mbase)                                                 \
        __builtin_amdgcn_s_setprio(1);                                          \
        _Pragma("unroll")                                                       \
        for (int m = 0; m < 4; m++)                                             \
            _Pragma("unroll")                                                   \
            for (int n = 0; n < 4; n++)                                         \
                acc[(mbase) + m][n] = __builtin_amdgcn_mfma_f32_16x16x32_bf16(  \
                    af[m].b, bf[n].b, acc[(mbase) + m][n], 0, 0, 0);            \
        __builtin_amdgcn_s_setprio(0);

    // Prologue: stage tile 0 fully (order A0,B0,A1,B1), confirm A0,B0 landed.
    STAGE(0, 0, 0, 0, gA); STAGE(0, 1, 0, 0, gB);
    STAGE(0, 0, 1, 0, gA); STAGE(0, 1, 1, 0, gB);
    WVM4;
    SBAR;

    for (int t = 0; t < 64; t++) {
        const int cur = t & 1, nxt = cur ^ 1;
        const int ktn = (t + 1) & 63;     // last tile re-stages tile 0 (uniform count)
        FragCvt a[4], b[4];

        // q0: kh0, acc rows 0..3
        LDA4(a, cur, 0, 0); LDB4(b, cur, 0);
        STAGE(nxt, 0, 0, ktn, gA);
        SBAR;
        MM16(a, b, 0);
        SBAR;

        // q1: kh0, acc rows 4..7 (reuse b)
        LDA4(a, cur, 0, 4);
        STAGE(nxt, 1, 0, ktn, gB);
        WVM4;                              // A1(t),B1(t) landed; 4 loads in flight
        SBAR;
        MM16(a, b, 4);
        SBAR;

        // q2: kh1, acc rows 0..3
        LDA4(a, cur, 1, 0); LDB4(b, cur, 1);
        STAGE(nxt, 0, 1, ktn, gA);
        SBAR;
        MM16(a, b, 0);
        SBAR;

        // q3: kh1, acc rows 4..7
        LDA4(a, cur, 1, 4);
        STAGE(nxt, 1, 1, ktn, gB);
        WVM4;                              // A0(t+1),B0(t+1) landed; 4 in flight
        SBAR;
        MM16(a, b, 4);
        SBAR;
    }
    asm volatile("s_waitcnt vmcnt(0)" ::: "memory");

    // Epilogue: C = acc + bias
    const int colbase = bn * 256 + wn * 64 + lr;
    const int rowbase = bm * 256 + wm * 128 + lk * 4;
    #pragma unroll
    for (int n = 0; n < 4; n++) {
        float bv = bias[colbase + n * 16];
        #pragma unroll
        for (int m = 0; m < 8; m++) {
            #pragma unroll
            for (int r = 0; r < 4; r++)
                C[(size_t)(rowbase + m * 16 + r) * N_DIM + colbase + n * 16] = acc[m][n][r] + bv;
        }
    }
    #undef STAGE
    #undef LDA4
    #undef LDB4
    #undef MM16
}

// ---------------- fallback (tiny ws): masked f32 GEMM ----------------
__global__ void k_gemm_f32(const float* __restrict__ A, const float* __restrict__ W,
                           const uint32_t* __restrict__ ctrl, const float* __restrict__ bias,
                           float* __restrict__ C) {
    __shared__ float sA[16][64];
    __shared__ float sW[16][65];
    float T = __uint_as_float(ctrl[C_TBITS]);
    int bx = blockIdx.x % (N_DIM / 16), by = blockIdx.x / (N_DIM / 16);
    int tx = threadIdx.x & 15, ty = threadIdx.x >> 4;
    float acc = 0.f;
    for (int k0 = 0; k0 < K_DIM; k0 += 64) {
        for (int j = threadIdx.x; j < 16 * 64; j += 256) {
            int r = j >> 6, c = j & 63;
            sA[r][c] = A[(size_t)(by * 16 + r) * K_DIM + k0 + c];
            float w = W[(size_t)(bx * 16 + r) * K_DIM + k0 + c];
            sW[r][c] = (fabsf(w) >= T) ? w : 0.f;
        }
        __syncthreads();
#pragma unroll 16
        for (int kk = 0; kk < 64; kk++) acc += sA[ty][kk] * sW[tx][kk];
        __syncthreads();
    }
    C[(size_t)(by * 16 + ty) * N_DIM + bx * 16 + tx] = acc + bias[bx * 16 + tx];
}

extern "C" void kernel_launch(void* const* d_in, const int* in_sizes, int n_in,
                              void* d_out, int out_size, void* d_ws, size_t ws_size,
                              hipStream_t stream) {
    const float* x    = (const float*)d_in[0];
    const float* w    = (const float*)d_in[1];
    const float* bias = (const float*)d_in[2];
    float* out = (float*)d_out;
    char* ws = (char*)d_ws;

    uint32_t* ctrl  = (uint32_t*)(ws + WS_CTRL);
    uint32_t* h1    = (uint32_t*)(ws + WS_H1);
    uint32_t* h2a   = (uint32_t*)(ws + WS_H2A);
    uint32_t* h2b   = (uint32_t*)(ws + WS_H2B);
    uint32_t* listA = (uint32_t*)(ws + WS_LISTA);
    uint32_t* listB = (uint32_t*)(ws + WS_LISTB);

    hipMemsetAsync(d_ws, 0, WS_ZERO_BYTES, stream);
    k_hist1 <<<1024, 256, 0, stream>>>((const uint32_t*)w, h1);
    k_sel1  <<<1,    256, 0, stream>>>(h1, ctrl);
    k_hist2 <<<1024, 256, 0, stream>>>((const uint32_t*)w, ctrl, h2a, h2b);
    k_sel2  <<<1,    256, 0, stream>>>(h2a, h2b, ctrl);
    k_gather<<<1024, 256, 0, stream>>>((const uint32_t*)w, ctrl, listA, listB);
    k_final <<<1,     64, 0, stream>>>(listA, listB, ctrl);

    if (ws_size >= WS_NEED) {
        ushort_t* Abf = (ushort_t*)(ws + WS_ABF);
        ushort_t* Wbf = (ushort_t*)(ws + WS_WBF);
        k_convA<<<2048, 256, 0, stream>>>((const float4*)x, (ushort4*)Abf, (M_DIM * K_DIM) / 4);
        k_maskW<<<1024, 256, 0, stream>>>((const float4*)w, ctrl, (ushort4*)Wbf, N_W / 4);
        k_gemm256<<<(M_DIM / 256) * (N_DIM / 256), 512, 0, stream>>>(Abf, Wbf, bias, out);
    } else {
        k_gemm_f32<<<(M_DIM / 16) * (N_DIM / 16), 256, 0, stream>>>(x, w, ctrl, bias, out);
    }
}